// Round 5
// baseline (1228.216 us; speedup 1.0000x reference)
//
#include <hip/hip_runtime.h>
#include <hip/hip_bf16.h>

// Shapes (fixed for this problem)
constexpr int B = 2, N = 512, H = 12, C = 16, PQ = 4, PV = 8, CZ = 128, CS = 384;
constexpr int HC   = H * C;            // 192
constexpr int QP3 = H * PQ * 3;        // 144
constexpr int VP3 = H * PV * 3;        // 288
constexpr int FEAT = (CZ + C + PV * 4) * H; // 2112
constexpr float QK_SCALE  = 0.14433756729740643f;  // (3*C)^-0.5
constexpr float INV_SQRT3 = 0.5773502691896258f;
constexpr float WC_IS3    = 0.13608276348795434f;  // sqrt(2/(9*PQ))*3^-0.5

using f32x4 = __attribute__((ext_vector_type(4))) float;
using s16x8 = __attribute__((ext_vector_type(8))) short;
using s16x4 = __attribute__((ext_vector_type(4))) short;

__device__ __forceinline__ short f2b(float f) {
    union { __hip_bfloat16 b; short s; } u;
    u.b = __float2bfloat16(f);
    return u.s;
}

// ---------------------------------------------------------------------------
// Kernel 1: projections + packing. 8 rows/block, 128 blocks.
// Emits: qcw bf16[1024][192] (QK_SCALE*q), kkp bf16[1024][384]
//   ([0..191]=k, [192+16h+e]: e<12 kp, e=12 kpsq, 13..15 zero),
// vT f32[B][192][N], vpT f32[B][288][N],
// pcw bf16[1024][192] ({-2pac*qp | pac | 0,0,0} per h), auxw f32[1024][16].
// ---------------------------------------------------------------------------
constexpr int RPB = 8;

__global__ __launch_bounds__(256) void k_proj(
    const float* __restrict__ s, const float* __restrict__ rot, const float* __restrict__ trans,
    const float* __restrict__ Wq, const float* __restrict__ bq,
    const float* __restrict__ Wkv, const float* __restrict__ bkv,
    const float* __restrict__ Wqp, const float* __restrict__ bqp,
    const float* __restrict__ Wkvp, const float* __restrict__ bkvp,
    const float* __restrict__ gamma, const float* __restrict__ bb,
    short* __restrict__ qcw, short* __restrict__ kkp,
    float* __restrict__ vT, float* __restrict__ vpT,
    short* __restrict__ pcw, float* __restrict__ auxw)
{
    __shared__ float s_s[RPB][CS];          // 12 KB
    __shared__ float rawqp_s[RPB][144];
    __shared__ float rawkvp_s[RPB][432];
    __shared__ float qrot_s[RPB][48][3];
    __shared__ float sq_s[RPB][48];
    __shared__ float R_s[RPB][9], T_s[RPB][3];
    const int t = threadIdx.x;
    const int bi0 = blockIdx.x * RPB;

    for (int idx = t; idx < RPB * CS / 4; idx += 256) {
        int r = idx / (CS / 4), k4 = idx % (CS / 4);
        ((float4*)s_s[r])[k4] = ((const float4*)(s + (size_t)(bi0 + r) * CS))[k4];
    }
    if (t < RPB * 9) R_s[t / 9][t % 9] = rot[bi0 * 9 + t];
    if (t < RPB * 3) T_s[t / 3][t % 3] = trans[bi0 * 3 + t];
    __syncthreads();

    // phase B: all 4 projections, W read once per block
    for (int cg = 0; cg < 5; ++cg) {
        int c = t + 256 * cg;
        if (c >= 1152) break;
        const float* Wp; int ldw; float bv;
        if (c < 192)      { Wp = Wq   + c;        ldw = 192; bv = bq[c]; }
        else if (c < 576) { Wp = Wkv  + (c - 192); ldw = 384; bv = bkv[c - 192]; }
        else if (c < 720) { Wp = Wqp  + (c - 576); ldw = 144; bv = bqp[c - 576]; }
        else              { Wp = Wkvp + (c - 720); ldw = 432; bv = bkvp[c - 720]; }
        float acc[RPB];
        #pragma unroll
        for (int r = 0; r < RPB; ++r) acc[r] = bv;
        for (int k4 = 0; k4 < CS / 4; ++k4) {
            float4 sv[RPB];
            #pragma unroll
            for (int r = 0; r < RPB; ++r) sv[r] = *(const float4*)&s_s[r][k4 * 4];
            #pragma unroll
            for (int e = 0; e < 4; ++e) {
                float wv = Wp[(size_t)(k4 * 4 + e) * ldw];
                #pragma unroll
                for (int r = 0; r < RPB; ++r)
                    acc[r] += ((const float*)&sv[r])[e] * wv;
            }
        }
        if (c < 192) {
            #pragma unroll
            for (int r = 0; r < RPB; ++r)
                qcw[(size_t)(bi0 + r) * 192 + c] = f2b(QK_SCALE * acc[r]);
        } else if (c < 576) {
            int cc = c - 192, h = cc >> 5, w5 = cc & 31;
            if (w5 < 16) {
                #pragma unroll
                for (int r = 0; r < RPB; ++r)
                    kkp[(size_t)(bi0 + r) * 384 + h * 16 + w5] = f2b(acc[r]);
            } else {
                #pragma unroll
                for (int r = 0; r < RPB; ++r) {
                    int row = bi0 + r, bq_ = row >> 9, iq = row & (N - 1);
                    vT[((size_t)bq_ * 192 + h * 16 + (w5 - 16)) * N + iq] = acc[r];
                }
            }
        } else if (c < 720) {
            #pragma unroll
            for (int r = 0; r < RPB; ++r) rawqp_s[r][c - 576] = acc[r];
        } else {
            #pragma unroll
            for (int r = 0; r < RPB; ++r) rawkvp_s[r][c - 720] = acc[r];
        }
    }
    __syncthreads();

    // phase C: rotations
    for (int idx = t; idx < RPB * 48; idx += 256) {
        int r = idx / 48, p = idx % 48;
        float y0 = rawqp_s[r][p], y1 = rawqp_s[r][48 + p], y2 = rawqp_s[r][96 + p];
        #pragma unroll
        for (int x = 0; x < 3; ++x)
            qrot_s[r][p][x] = T_s[r][x] + R_s[r][x * 3] * y0 + R_s[r][x * 3 + 1] * y1 + R_s[r][x * 3 + 2] * y2;
    }
    for (int idx = t; idx < RPB * 144; idx += 256) {
        int r = idx / 144, p = idx % 144, h = p / 12, pp = p % 12;
        float y0 = rawkvp_s[r][p], y1 = rawkvp_s[r][144 + p], y2 = rawkvp_s[r][288 + p];
        float vals[3]; float ss = 0.0f;
        #pragma unroll
        for (int x = 0; x < 3; ++x) {
            float v = T_s[r][x] + R_s[r][x * 3] * y0 + R_s[r][x * 3 + 1] * y1 + R_s[r][x * 3 + 2] * y2;
            vals[x] = v; ss += v * v;
        }
        int row = bi0 + r, bq_ = row >> 9, iq = row & (N - 1);
        if (pp < PQ) {
            #pragma unroll
            for (int x = 0; x < 3; ++x)
                kkp[(size_t)row * 384 + 192 + h * 16 + pp * 3 + x] = f2b(vals[x]);
            sq_s[r][h * 4 + pp] = ss;
        } else {
            #pragma unroll
            for (int x = 0; x < 3; ++x)
                vpT[((size_t)bq_ * 288 + h * 24 + (pp - PQ) * 3 + x) * N + iq] = vals[x];
        }
    }
    __syncthreads();

    // phase D: per (row, h) epilogue
    if (t < RPB * 12) {
        int r = t / 12, h = t % 12, row = bi0 + r;
        float g = gamma[h];
        float sp = fmaxf(g, 0.0f) + log1pf(expf(-fabsf(g)));
        float pac = -0.5f * sp * WC_IS3;
        float kpsq = sq_s[r][h * 4] + sq_s[r][h * 4 + 1] + sq_s[r][h * 4 + 2] + sq_s[r][h * 4 + 3];
        kkp[(size_t)row * 384 + 192 + h * 16 + 12] = f2b(kpsq);
        kkp[(size_t)row * 384 + 192 + h * 16 + 13] = 0;
        kkp[(size_t)row * 384 + 192 + h * 16 + 14] = 0;
        kkp[(size_t)row * 384 + 192 + h * 16 + 15] = 0;
        float qpsq = 0.0f;
        #pragma unroll
        for (int pq = 0; pq < 4; ++pq)
            #pragma unroll
            for (int x = 0; x < 3; ++x) {
                float qv = qrot_s[r][h * 4 + pq][x];
                qpsq += qv * qv;
                pcw[(size_t)row * 192 + h * 16 + pq * 3 + x] = f2b(-2.0f * pac * qv);
            }
        pcw[(size_t)row * 192 + h * 16 + 12] = f2b(pac);
        pcw[(size_t)row * 192 + h * 16 + 13] = 0;
        pcw[(size_t)row * 192 + h * 16 + 14] = 0;
        pcw[(size_t)row * 192 + h * 16 + 15] = 0;
        auxw[(size_t)row * 16 + h] = INV_SQRT3 * bb[h] + pac * qpsq;
    }
    if (t >= RPB * 12 && t < RPB * 16) {
        int r = (t - 96) >> 2, hh = 12 + ((t - 96) & 3);
        auxw[(size_t)(bi0 + r) * 16 + hh] = 0.0f;
    }
}

// ---------------------------------------------------------------------------
// Kernel 2: fused attention. Block = (b,i), 4 waves, wave owns 128 j's.
// Logits: 16 chained 16x16x32 bf16 MFMAs (z@Wb + kkp with compact B-selects).
// opair: 16x16x16 MFMA, P already in A-layout. o/op: VALU from vT/vpT.
// ---------------------------------------------------------------------------
__global__ __launch_bounds__(256, 4) void k_attn(
    const float* __restrict__ z, const float* __restrict__ rot, const float* __restrict__ trans,
    const float* __restrict__ seq_mask,
    const float* __restrict__ Wb,
    const short* __restrict__ qcw, const short* __restrict__ kkp,
    const float* __restrict__ vT, const float* __restrict__ vpT,
    const short* __restrict__ pcw, const float* __restrict__ auxw,
    float* __restrict__ feat)
{
    __shared__ __align__(16) float smem_u[8064];   // 32256 B overlay
    float* P_s = smem_u;                   // loop: [4][192] = [w][h*16+j]
    float* opm = smem_u;                   // merge: [4][1536]
    float* om  = smem_u + 6144;            // merge: [4][192]
    float* vpm = smem_u + 6912;            // merge: [4][288]
    __shared__ float ml_s[4][16], ll_s[4][16], M_s[16], Linv_s[16];
    __shared__ float R_s[9], T_s[3];

    const int t = threadIdx.x;
    const int w   = t >> 6;
    const int l   = t & 63;
    const int lg  = l >> 4;
    const int m15 = l & 15;
    const int bi  = blockIdx.x;
    const int b   = bi >> 9;
    const int i   = bi & (N - 1);

    if (t < 9) R_s[t] = rot[bi * 9 + t];
    if (t < 3) T_s[t] = trans[bi * 3 + t];

    const bool hv = (m15 < 12);
    const int hcl = hv ? m15 : 0;
    const int half = m15 >> 1;
    const float constH = auxw[(size_t)bi * 16 + m15];
    const float mask_i = seq_mask[bi];

    const s16x8 z8 = {0, 0, 0, 0, 0, 0, 0, 0};
    // WbB: B[c][h] = INV_SQRT3 * Wb[c][h]
    s16x8 WbB[4];
    #pragma unroll
    for (int kk = 0; kk < 4; ++kk) {
        s16x8 f;
        #pragma unroll
        for (int e = 0; e < 8; ++e) {
            int c = kk * 32 + lg * 8 + e;
            f[e] = f2b(hv ? INV_SQRT3 * Wb[c * H + hcl] : 0.0f);
        }
        WbB[kk] = f;
    }
    // compact h-aligned B selects for qk and pa terms
    s16x8 qsel, psel;
    {
        const bool selh = ((lg >> 1) == (m15 & 1));
        const short* qrow = qcw + (size_t)bi * 192 + hcl * 16;
        s16x8 qlo = *(const s16x8*)qrow;
        s16x8 qhi = *(const s16x8*)(qrow + 8);
        qsel = (hv && selh) ? ((lg & 1) ? qhi : qlo) : z8;
        const short* prow = pcw + (size_t)bi * 192 + hcl * 16;
        s16x8 plo = *(const s16x8*)prow;
        s16x8 phi = *(const s16x8*)(prow + 8);
        psel = (hv && selh) ? ((lg & 1) ? phi : plo) : z8;
    }

    float m_run = -INFINITY, l_run = 0.0f;
    f32x4 opacc[8];
    #pragma unroll
    for (int ct = 0; ct < 8; ++ct) opacc[ct] = (f32x4){0.0f, 0.0f, 0.0f, 0.0f};
    float oacc[3] = {0.0f, 0.0f, 0.0f};
    float vpacc[2][3] = {{0, 0, 0}, {0, 0, 0}};

    const size_t zbase = ((size_t)b * N + i) * (size_t)(N * CZ);
    const int jw = w * 128;
    const float* zAp = z + zbase + (size_t)(jw + m15) * CZ + lg * 8;
    const short* kAp = kkp + (size_t)(b * N + jw + m15) * 384 + lg * 8;
    const float* zBp = z + zbase + (size_t)(jw + lg * 4) * CZ + m15;
    const float* mkp = seq_mask + b * N + jw + lg * 4;
    float* Pw = P_s + w * 192;

    for (int jc = 0; jc < 8; ++jc) {
        const int j0 = jw + jc * 16;
        // ---- A-fragments ----
        s16x8 zf[4];
        #pragma unroll
        for (int kk = 0; kk < 4; ++kk) {
            float4 u0 = *(const float4*)(zAp + kk * 32);
            float4 u1 = *(const float4*)(zAp + kk * 32 + 4);
            s16x8 f;
            f[0] = f2b(u0.x); f[1] = f2b(u0.y); f[2] = f2b(u0.z); f[3] = f2b(u0.w);
            f[4] = f2b(u1.x); f[5] = f2b(u1.y); f[6] = f2b(u1.z); f[7] = f2b(u1.w);
            zf[kk] = f;
        }
        s16x8 kkpf[12];
        #pragma unroll
        for (int kk = 0; kk < 12; ++kk) kkpf[kk] = *(const s16x8*)(kAp + kk * 32);

        // ---- chained logit MFMAs: D[j][h] ----
        f32x4 acc = (f32x4){0.0f, 0.0f, 0.0f, 0.0f};
        #pragma unroll
        for (int kk = 0; kk < 4; ++kk)
            acc = __builtin_amdgcn_mfma_f32_16x16x32_bf16(zf[kk], WbB[kk], acc, 0, 0, 0);
        #pragma unroll
        for (int kk = 0; kk < 12; ++kk) {
            s16x8 bsel;
            if (kk < 6) bsel = (kk == half) ? qsel : z8;
            else        bsel = ((kk - 6) == half) ? psel : z8;
            acc = __builtin_amdgcn_mfma_f32_16x16x32_bf16(kkpf[kk], bsel, acc, 0, 0, 0);
        }

        // ---- logits + online softmax (lane: h=m15, j = j0+lg*4+r) ----
        float4 m4 = *(const float4*)(mkp + jc * 16);
        float lo[4]; float cm = -INFINITY;
        #pragma unroll
        for (int r = 0; r < 4; ++r) {
            lo[r] = acc[r] + constH + 100000.0f * (mask_i * ((const float*)&m4)[r] - 1.0f);
            cm = fmaxf(cm, lo[r]);
        }
        cm = fmaxf(cm, __shfl_xor(cm, 16, 64));
        cm = fmaxf(cm, __shfl_xor(cm, 32, 64));
        float mnew = fmaxf(m_run, cm);
        float sc = __expf(m_run - mnew);
        m_run = mnew;
        float p[4]; float ps = 0.0f;
        #pragma unroll
        for (int r = 0; r < 4; ++r) { p[r] = __expf(lo[r] - mnew); ps += p[r]; }
        ps += __shfl_xor(ps, 16, 64);
        ps += __shfl_xor(ps, 32, 64);
        l_run = l_run * sc + ps;

        if (hv) *(float4*)&Pw[m15 * 16 + lg * 4] = (float4){p[0], p[1], p[2], p[3]};

        // ---- opair MFMA: D[h][c], A = P in-layout, B = z col gathers ----
        s16x4 pfrag;
        #pragma unroll
        for (int r = 0; r < 4; ++r) pfrag[r] = hv ? f2b(p[r]) : (short)0;
        float s4[4];
        #pragma unroll
        for (int r = 0; r < 4; ++r) s4[r] = __shfl(sc, lg * 4 + r, 64);
        #pragma unroll
        for (int ct = 0; ct < 8; ++ct) {
            s16x4 bfr;
            #pragma unroll
            for (int e = 0; e < 4; ++e) bfr[e] = f2b(zBp[(size_t)e * CZ + ct * 16]);
            f32x4 oa = opacc[ct];
            #pragma unroll
            for (int r = 0; r < 4; ++r) oa[r] *= s4[r];
            opacc[ct] = __builtin_amdgcn_mfma_f32_16x16x16bf16_1k(pfrag, bfr, oa, 0, 0, 0);
        }

        // ---- o: VALU, vT rows (16 consecutive j) ----
        #pragma unroll
        for (int rr = 0; rr < 3; ++rr) {
            int oi = l + 64 * rr, oh = oi >> 4;
            float so = __shfl(sc, oh, 64);
            const float* vr = vT + ((size_t)b * 192 + oi) * N + j0;
            float a = oacc[rr] * so;
            #pragma unroll
            for (int q4 = 0; q4 < 4; ++q4) {
                float4 v4 = *(const float4*)(vr + q4 * 4);
                float4 P4 = *(const float4*)&Pw[oh * 16 + q4 * 4];
                a += P4.x * v4.x + P4.y * v4.y + P4.z * v4.z + P4.w * v4.w;
            }
            oacc[rr] = a;
        }
        // ---- op: VALU, vpT rows ----
        #pragma unroll
        for (int rr = 0; rr < 2; ++rr) {
            int oi = l + 64 * rr;
            int ohc = (oi < 96) ? (oi >> 3) : 0;
            float so = __shfl(sc, ohc, 64);
            if (oi < 96) {
                float a[3];
                #pragma unroll
                for (int x = 0; x < 3; ++x) a[x] = vpacc[rr][x] * so;
                float4 P4[4];
                #pragma unroll
                for (int q4 = 0; q4 < 4; ++q4) P4[q4] = *(const float4*)&Pw[ohc * 16 + q4 * 4];
                #pragma unroll
                for (int x = 0; x < 3; ++x) {
                    const float* vr = vpT + ((size_t)b * 288 + oi * 3 + x) * N + j0;
                    #pragma unroll
                    for (int q4 = 0; q4 < 4; ++q4) {
                        float4 v4 = *(const float4*)(vr + q4 * 4);
                        a[x] += P4[q4].x * v4.x + P4[q4].y * v4.y + P4[q4].z * v4.z + P4[q4].w * v4.w;
                    }
                }
                #pragma unroll
                for (int x = 0; x < 3; ++x) vpacc[rr][x] = a[x];
            }
        }
        zAp += 16 * CZ; kAp += 16 * 384; zBp += 16 * CZ;
    }

    // ---- merge the 4 waves ----
    if (lg == 0) { ml_s[w][m15] = m_run; ll_s[w][m15] = l_run; }
    __syncthreads();
    if (t < 12) {
        float M = ml_s[0][t];
        M = fmaxf(M, ml_s[1][t]); M = fmaxf(M, ml_s[2][t]); M = fmaxf(M, ml_s[3][t]);
        float Lt = 0.0f;
        #pragma unroll
        for (int ww = 0; ww < 4; ++ww) Lt += ll_s[ww][t] * __expf(ml_s[ww][t] - M);
        M_s[t] = M;
        Linv_s[t] = 1.0f / Lt;
    }
    __syncthreads();
    {
        float e4[4];
        #pragma unroll
        for (int r = 0; r < 4; ++r) {
            int hr = lg * 4 + r;
            e4[r] = (hr < 12) ? __expf(ml_s[w][hr] - M_s[hr]) : 0.0f;
        }
        #pragma unroll
        for (int ct = 0; ct < 8; ++ct)
            #pragma unroll
            for (int r = 0; r < 4; ++r) {
                int hr = lg * 4 + r;
                if (hr < 12) opm[w * 1536 + hr * 128 + ct * 16 + m15] = opacc[ct][r] * e4[r];
            }
        #pragma unroll
        for (int rr = 0; rr < 3; ++rr) {
            int oi = l + 64 * rr, oh = oi >> 4;
            om[w * 192 + oi] = oacc[rr] * __expf(ml_s[w][oh] - M_s[oh]);
        }
        #pragma unroll
        for (int rr = 0; rr < 2; ++rr) {
            int oi = l + 64 * rr;
            if (oi < 96) {
                int oh = oi >> 3;
                float sw = __expf(ml_s[w][oh] - M_s[oh]);
                #pragma unroll
                for (int x = 0; x < 3; ++x) vpm[w * 288 + oi * 3 + x] = vpacc[rr][x] * sw;
            }
        }
    }
    __syncthreads();

    float* F = feat + (size_t)bi * FEAT;
    if (t < HC) F[t] = (om[t] + om[192 + t] + om[384 + t] + om[576 + t]) * Linv_s[t >> 4];
    #pragma unroll
    for (int r = 0; r < 6; ++r) {
        int v = t + 256 * r; int hh = v >> 7;
        F[576 + v] = (opm[v] + opm[1536 + v] + opm[3072 + v] + opm[4608 + v]) * Linv_s[hh];
    }
    if (t < 96) {
        int hh = t >> 3; float il = Linv_s[hh];
        float o0 = (vpm[t * 3 + 0] + vpm[288 + t * 3 + 0] + vpm[576 + t * 3 + 0] + vpm[864 + t * 3 + 0]) * il - T_s[0];
        float o1 = (vpm[t * 3 + 1] + vpm[288 + t * 3 + 1] + vpm[576 + t * 3 + 1] + vpm[864 + t * 3 + 1]) * il - T_s[1];
        float o2 = (vpm[t * 3 + 2] + vpm[288 + t * 3 + 2] + vpm[576 + t * 3 + 2] + vpm[864 + t * 3 + 2]) * il - T_s[2];
        float n2 = 0.0f;
        #pragma unroll
        for (int x = 0; x < 3; ++x) {
            float rx = R_s[0 * 3 + x] * o0 + R_s[1 * 3 + x] * o1 + R_s[2 * 3 + x] * o2; // R^T
            F[HC + 96 * x + t] = rx;
            n2 += rx * rx;
        }
        F[480 + t] = fmaxf(sqrtf(n2), 1e-6f);
    }
}

// ---------------------------------------------------------------------------
// Kernel 3: tiled f32 GEMM  out[1024,384] = feat[1024,2112] @ Wout + bout.
// ---------------------------------------------------------------------------
constexpr int BM = 32, BN = 64, KC = 96;
constexpr int FP = 100;

__global__ __launch_bounds__(256) void k_out(
    const float* __restrict__ feat, const float* __restrict__ Wout, const float* __restrict__ bout,
    float* __restrict__ out)
{
    __shared__ float f_s[BM * FP];
    __shared__ float w_s[KC * BN];
    const int t = threadIdx.x;
    const int bm = (blockIdx.x / 6) * BM;
    const int bn = (blockIdx.x % 6) * BN;

    const int cg = t & 15;
    const int rp = t >> 4;
    const int r0 = rp, r1 = rp + 16;

    float4 acc0 = {0, 0, 0, 0}, acc1 = {0, 0, 0, 0};

    for (int k0 = 0; k0 < FEAT; k0 += KC) {
        __syncthreads();
        for (int idx = t; idx < BM * KC / 4; idx += 256) {
            int row = idx / (KC / 4), c4 = idx % (KC / 4);
            *(float4*)&f_s[row * FP + c4 * 4] =
                *(const float4*)&feat[(size_t)(bm + row) * FEAT + k0 + c4 * 4];
        }
        for (int idx = t; idx < KC * BN / 4; idx += 256) {
            int row = idx >> 4, c4 = idx & 15;
            *(float4*)&w_s[row * BN + c4 * 4] =
                *(const float4*)&Wout[(size_t)(k0 + row) * CS + bn + c4 * 4];
        }
        __syncthreads();

        #pragma unroll 4
        for (int kq = 0; kq < KC / 4; ++kq) {
            float4 fa = *(const float4*)&f_s[r0 * FP + kq * 4];
            float4 fb = *(const float4*)&f_s[r1 * FP + kq * 4];
            const float fav[4] = {fa.x, fa.y, fa.z, fa.w};
            const float fbv[4] = {fb.x, fb.y, fb.z, fb.w};
            #pragma unroll
            for (int e = 0; e < 4; ++e) {
                float4 w4 = *(const float4*)&w_s[(kq * 4 + e) * BN + cg * 4];
                acc0.x += fav[e] * w4.x; acc0.y += fav[e] * w4.y;
                acc0.z += fav[e] * w4.z; acc0.w += fav[e] * w4.w;
                acc1.x += fbv[e] * w4.x; acc1.y += fbv[e] * w4.y;
                acc1.z += fbv[e] * w4.z; acc1.w += fbv[e] * w4.w;
            }
        }
    }

    float4 bo = *(const float4*)&bout[bn + cg * 4];
    acc0.x += bo.x; acc0.y += bo.y; acc0.z += bo.z; acc0.w += bo.w;
    acc1.x += bo.x; acc1.y += bo.y; acc1.z += bo.z; acc1.w += bo.w;
    *(float4*)&out[(size_t)(bm + r0) * CS + bn + cg * 4] = acc0;
    *(float4*)&out[(size_t)(bm + r1) * CS + bn + cg * 4] = acc1;
}

// ---------------------------------------------------------------------------
extern "C" void kernel_launch(void* const* d_in, const int* in_sizes, int n_in,
                              void* d_out, int out_size, void* d_ws, size_t ws_size,
                              hipStream_t stream)
{
    const float* s     = (const float*)d_in[0];
    const float* z     = (const float*)d_in[1];
    const float* rot   = (const float*)d_in[2];
    const float* trans = (const float*)d_in[3];
    const float* mask  = (const float*)d_in[4];
    const float* Wq    = (const float*)d_in[5];
    const float* bq    = (const float*)d_in[6];
    const float* Wkv   = (const float*)d_in[7];
    const float* bkv   = (const float*)d_in[8];
    const float* Wb    = (const float*)d_in[9];
    const float* bb    = (const float*)d_in[10];
    const float* Wqp   = (const float*)d_in[11];
    const float* bqp   = (const float*)d_in[12];
    const float* Wkvp  = (const float*)d_in[13];
    const float* bkvp  = (const float*)d_in[14];
    const float* gamma = (const float*)d_in[15];
    const float* Wout  = (const float*)d_in[16];
    const float* bout  = (const float*)d_in[17];

    // workspace layout (bytes), all 16B-aligned; total 12,255,232
    char* wsb = (char*)d_ws;
    float* feat = (float*)wsb;                       // 8,650,752
    float* vT   = (float*)(wsb + 8650752);           //   786,432
    float* vpT  = (float*)(wsb + 9437184);           // 1,179,648
    float* auxw = (float*)(wsb + 10616832);          //    65,536
    short* qcw  = (short*)(wsb + 10682368);          //   393,216
    short* pcw  = (short*)(wsb + 11075584);          //   393,216
    short* kkp  = (short*)(wsb + 11468800);          //   786,432

    dim3 blk(256);
    hipLaunchKernelGGL(k_proj, dim3(B * N / RPB), blk, 0, stream,
                       s, rot, trans, Wq, bq, Wkv, bkv, Wqp, bqp, Wkvp, bkvp,
                       gamma, bb, qcw, kkp, vT, vpT, pcw, auxw);
    hipLaunchKernelGGL(k_attn, dim3(B * N), blk, 0, stream,
                       z, rot, trans, mask, Wb, qcw, kkp, vT, vpT, pcw, auxw, feat);
    hipLaunchKernelGGL(k_out, dim3(192), blk, 0, stream,
                       feat, Wout, bout, (float*)d_out);
}

// Round 7
// 561.957 us; speedup vs baseline: 2.1856x; 2.1856x over previous
//
#include <hip/hip_runtime.h>
#include <hip/hip_bf16.h>

// Shapes (fixed for this problem)
constexpr int B = 2, N = 512, H = 12, C = 16, PQ = 4, PV = 8, CZ = 128, CS = 384;
constexpr int HC   = H * C;            // 192
constexpr int FEAT = (CZ + C + PV * 4) * H; // 2112
constexpr float QK_SCALE  = 0.14433756729740643f;  // (3*C)^-0.5
constexpr float INV_SQRT3 = 0.5773502691896258f;
constexpr float WC_IS3    = 0.13608276348795434f;  // sqrt(2/(9*PQ))*3^-0.5

using f32x4 = __attribute__((ext_vector_type(4))) float;
using s16x8 = __attribute__((ext_vector_type(8))) short;

__device__ __forceinline__ short f2b(float f) {
    union { __hip_bfloat16 b; short s; } u;
    u.b = __float2bfloat16(f);
    return u.s;
}
__device__ __forceinline__ float b2f(short s) {
    union { short s; __hip_bfloat16 b; } u;
    u.s = s;
    return __bfloat162float(u.b);
}

// ---------------------------------------------------------------------------
// Kernel 1: projections + packing. 8 rows/block, 128 blocks. (unchanged)
// ---------------------------------------------------------------------------
constexpr int RPB = 8;

__global__ __launch_bounds__(256) void k_proj(
    const float* __restrict__ s, const float* __restrict__ rot, const float* __restrict__ trans,
    const float* __restrict__ Wq, const float* __restrict__ bq,
    const float* __restrict__ Wkv, const float* __restrict__ bkv,
    const float* __restrict__ Wqp, const float* __restrict__ bqp,
    const float* __restrict__ Wkvp, const float* __restrict__ bkvp,
    const float* __restrict__ gamma, const float* __restrict__ bb,
    short* __restrict__ qcw, short* __restrict__ kkp,
    float* __restrict__ vT, float* __restrict__ vpT,
    short* __restrict__ pcw, float* __restrict__ auxw)
{
    __shared__ float s_s[RPB][CS];
    __shared__ float rawqp_s[RPB][144];
    __shared__ float rawkvp_s[RPB][432];
    __shared__ float qrot_s[RPB][48][3];
    __shared__ float sq_s[RPB][48];
    __shared__ float R_s[RPB][9], T_s[RPB][3];
    const int t = threadIdx.x;
    const int bi0 = blockIdx.x * RPB;

    for (int idx = t; idx < RPB * CS / 4; idx += 256) {
        int r = idx / (CS / 4), k4 = idx % (CS / 4);
        ((float4*)s_s[r])[k4] = ((const float4*)(s + (size_t)(bi0 + r) * CS))[k4];
    }
    if (t < RPB * 9) R_s[t / 9][t % 9] = rot[bi0 * 9 + t];
    if (t < RPB * 3) T_s[t / 3][t % 3] = trans[bi0 * 3 + t];
    __syncthreads();

    for (int cg = 0; cg < 5; ++cg) {
        int c = t + 256 * cg;
        if (c >= 1152) break;
        const float* Wp; int ldw; float bv;
        if (c < 192)      { Wp = Wq   + c;        ldw = 192; bv = bq[c]; }
        else if (c < 576) { Wp = Wkv  + (c - 192); ldw = 384; bv = bkv[c - 192]; }
        else if (c < 720) { Wp = Wqp  + (c - 576); ldw = 144; bv = bqp[c - 576]; }
        else              { Wp = Wkvp + (c - 720); ldw = 432; bv = bkvp[c - 720]; }
        float acc[RPB];
        #pragma unroll
        for (int r = 0; r < RPB; ++r) acc[r] = bv;
        for (int k4 = 0; k4 < CS / 4; ++k4) {
            float4 sv[RPB];
            #pragma unroll
            for (int r = 0; r < RPB; ++r) sv[r] = *(const float4*)&s_s[r][k4 * 4];
            #pragma unroll
            for (int e = 0; e < 4; ++e) {
                float wv = Wp[(size_t)(k4 * 4 + e) * ldw];
                #pragma unroll
                for (int r = 0; r < RPB; ++r)
                    acc[r] += ((const float*)&sv[r])[e] * wv;
            }
        }
        if (c < 192) {
            #pragma unroll
            for (int r = 0; r < RPB; ++r)
                qcw[(size_t)(bi0 + r) * 192 + c] = f2b(QK_SCALE * acc[r]);
        } else if (c < 576) {
            int cc = c - 192, h = cc >> 5, w5 = cc & 31;
            if (w5 < 16) {
                #pragma unroll
                for (int r = 0; r < RPB; ++r)
                    kkp[(size_t)(bi0 + r) * 384 + h * 16 + w5] = f2b(acc[r]);
            } else {
                #pragma unroll
                for (int r = 0; r < RPB; ++r) {
                    int row = bi0 + r, bq_ = row >> 9, iq = row & (N - 1);
                    vT[((size_t)bq_ * 192 + h * 16 + (w5 - 16)) * N + iq] = acc[r];
                }
            }
        } else if (c < 720) {
            #pragma unroll
            for (int r = 0; r < RPB; ++r) rawqp_s[r][c - 576] = acc[r];
        } else {
            #pragma unroll
            for (int r = 0; r < RPB; ++r) rawkvp_s[r][c - 720] = acc[r];
        }
    }
    __syncthreads();

    for (int idx = t; idx < RPB * 48; idx += 256) {
        int r = idx / 48, p = idx % 48;
        float y0 = rawqp_s[r][p], y1 = rawqp_s[r][48 + p], y2 = rawqp_s[r][96 + p];
        #pragma unroll
        for (int x = 0; x < 3; ++x)
            qrot_s[r][p][x] = T_s[r][x] + R_s[r][x * 3] * y0 + R_s[r][x * 3 + 1] * y1 + R_s[r][x * 3 + 2] * y2;
    }
    for (int idx = t; idx < RPB * 144; idx += 256) {
        int r = idx / 144, p = idx % 144, h = p / 12, pp = p % 12;
        float y0 = rawkvp_s[r][p], y1 = rawkvp_s[r][144 + p], y2 = rawkvp_s[r][288 + p];
        float vals[3]; float ss = 0.0f;
        #pragma unroll
        for (int x = 0; x < 3; ++x) {
            float v = T_s[r][x] + R_s[r][x * 3] * y0 + R_s[r][x * 3 + 1] * y1 + R_s[r][x * 3 + 2] * y2;
            vals[x] = v; ss += v * v;
        }
        int row = bi0 + r, bq_ = row >> 9, iq = row & (N - 1);
        if (pp < PQ) {
            #pragma unroll
            for (int x = 0; x < 3; ++x)
                kkp[(size_t)row * 384 + 192 + h * 16 + pp * 3 + x] = f2b(vals[x]);
            sq_s[r][h * 4 + pp] = ss;
        } else {
            #pragma unroll
            for (int x = 0; x < 3; ++x)
                vpT[((size_t)bq_ * 288 + h * 24 + (pp - PQ) * 3 + x) * N + iq] = vals[x];
        }
    }
    __syncthreads();

    if (t < RPB * 12) {
        int r = t / 12, h = t % 12, row = bi0 + r;
        float g = gamma[h];
        float sp = fmaxf(g, 0.0f) + log1pf(expf(-fabsf(g)));
        float pac = -0.5f * sp * WC_IS3;
        float kpsq = sq_s[r][h * 4] + sq_s[r][h * 4 + 1] + sq_s[r][h * 4 + 2] + sq_s[r][h * 4 + 3];
        kkp[(size_t)row * 384 + 192 + h * 16 + 12] = f2b(kpsq);
        kkp[(size_t)row * 384 + 192 + h * 16 + 13] = 0;
        kkp[(size_t)row * 384 + 192 + h * 16 + 14] = 0;
        kkp[(size_t)row * 384 + 192 + h * 16 + 15] = 0;
        float qpsq = 0.0f;
        #pragma unroll
        for (int pq = 0; pq < 4; ++pq)
            #pragma unroll
            for (int x = 0; x < 3; ++x) {
                float qv = qrot_s[r][h * 4 + pq][x];
                qpsq += qv * qv;
                pcw[(size_t)row * 192 + h * 16 + pq * 3 + x] = f2b(-2.0f * pac * qv);
            }
        pcw[(size_t)row * 192 + h * 16 + 12] = f2b(pac);
        pcw[(size_t)row * 192 + h * 16 + 13] = 0;
        pcw[(size_t)row * 192 + h * 16 + 14] = 0;
        pcw[(size_t)row * 192 + h * 16 + 15] = 0;
        auxw[(size_t)row * 16 + h] = INV_SQRT3 * bb[h] + pac * qpsq;
    }
    if (t >= RPB * 12 && t < RPB * 16) {
        int r = (t - 96) >> 2, hh = 12 + ((t - 96) & 3);
        auxw[(size_t)(bi0 + r) * 16 + hh] = 0.0f;
    }
}

// ---------------------------------------------------------------------------
// Kernel 2: fused attention, two phases through LDS P.
// Phase 1: logits via 16 chained MFMAs + online softmax -> P_lds (bf16),
//          wave merge, in-place normalize.  (FIX: advance zAp/kAp per chunk.)
// Phase 2: opair = P @ z via MFMA; o/op dots on vT/vpT; rotation epilogue.
// ---------------------------------------------------------------------------
__global__ __launch_bounds__(256) void k_attn2(
    const float* __restrict__ z, const float* __restrict__ rot, const float* __restrict__ trans,
    const float* __restrict__ seq_mask,
    const float* __restrict__ Wb,
    const short* __restrict__ qcw, const short* __restrict__ kkp,
    const short* __restrict__ pcw, const float* __restrict__ auxw,
    const float* __restrict__ vT, const float* __restrict__ vpT,
    float* __restrict__ feat)
{
    __shared__ short P_lds[16][512];        // 16 KB
    __shared__ float ml_s[4][16], ll_s[4][16], M_s[16], Linv_s[16];
    __shared__ float op_f[288];
    __shared__ float R_s[9], T_s[3];

    const int t = threadIdx.x;
    const int w   = t >> 6;
    const int l   = t & 63;
    const int lg  = l >> 4;
    const int m15 = l & 15;
    const int bi  = blockIdx.x;
    const int b   = bi >> 9;
    const int i   = bi & (N - 1);

    if (t < 9) R_s[t] = rot[bi * 9 + t];
    if (t < 3) T_s[t] = trans[bi * 3 + t];

    const bool hv = (m15 < 12);
    const int hcl = hv ? m15 : 0;
    const int half = m15 >> 1;
    const float constH = auxw[(size_t)bi * 16 + m15];
    const float mask_i = seq_mask[bi];

    const s16x8 z8 = {0, 0, 0, 0, 0, 0, 0, 0};
    s16x8 WbB[4];
    #pragma unroll
    for (int kk = 0; kk < 4; ++kk) {
        s16x8 f;
        #pragma unroll
        for (int e = 0; e < 8; ++e) {
            int c = kk * 32 + lg * 8 + e;
            f[e] = f2b(hv ? INV_SQRT3 * Wb[c * H + hcl] : 0.0f);
        }
        WbB[kk] = f;
    }
    s16x8 qsel, psel;
    {
        const bool selh = ((lg >> 1) == (m15 & 1));
        const short* qrow = qcw + (size_t)bi * 192 + hcl * 16;
        s16x8 qlo = *(const s16x8*)qrow;
        s16x8 qhi = *(const s16x8*)(qrow + 8);
        qsel = (hv && selh) ? ((lg & 1) ? qhi : qlo) : z8;
        const short* prow = pcw + (size_t)bi * 192 + hcl * 16;
        s16x8 plo = *(const s16x8*)prow;
        s16x8 phi = *(const s16x8*)(prow + 8);
        psel = (hv && selh) ? ((lg & 1) ? phi : plo) : z8;
    }

    float m_run = -INFINITY, l_run = 0.0f;

    const size_t zbase = ((size_t)b * N + i) * (size_t)(N * CZ);
    const int jw = w * 128;
    const float* zAp = z + zbase + (size_t)(jw + m15) * CZ + lg * 8;
    const short* kAp = kkp + (size_t)(b * N + jw + m15) * 384 + lg * 8;
    const float* mkp = seq_mask + b * N + jw + lg * 4;

    for (int jc = 0; jc < 8; ++jc) {
        // ---- A-fragments ----
        s16x8 zf[4];
        #pragma unroll
        for (int kk = 0; kk < 4; ++kk) {
            float4 u0 = *(const float4*)(zAp + kk * 32);
            float4 u1 = *(const float4*)(zAp + kk * 32 + 4);
            s16x8 f;
            f[0] = f2b(u0.x); f[1] = f2b(u0.y); f[2] = f2b(u0.z); f[3] = f2b(u0.w);
            f[4] = f2b(u1.x); f[5] = f2b(u1.y); f[6] = f2b(u1.z); f[7] = f2b(u1.w);
            zf[kk] = f;
        }
        s16x8 kkpf[12];
        #pragma unroll
        for (int kk = 0; kk < 12; ++kk) kkpf[kk] = *(const s16x8*)(kAp + kk * 32);

        // ---- chained logit MFMAs: D[j][h] ----
        f32x4 acc = (f32x4){0.0f, 0.0f, 0.0f, 0.0f};
        #pragma unroll
        for (int kk = 0; kk < 4; ++kk)
            acc = __builtin_amdgcn_mfma_f32_16x16x32_bf16(zf[kk], WbB[kk], acc, 0, 0, 0);
        #pragma unroll
        for (int kk = 0; kk < 12; ++kk) {
            s16x8 bsel;
            if (kk < 6) bsel = (kk == half) ? qsel : z8;
            else        bsel = ((kk - 6) == half) ? psel : z8;
            acc = __builtin_amdgcn_mfma_f32_16x16x32_bf16(kkpf[kk], bsel, acc, 0, 0, 0);
        }

        // ---- softmax (lane: h=m15, j = jw + jc*16 + lg*4 + r) ----
        float4 m4 = *(const float4*)(mkp + jc * 16);
        float lo[4]; float cm = -INFINITY;
        #pragma unroll
        for (int r = 0; r < 4; ++r) {
            lo[r] = acc[r] + constH + 100000.0f * (mask_i * ((const float*)&m4)[r] - 1.0f);
            cm = fmaxf(cm, lo[r]);
        }
        cm = fmaxf(cm, __shfl_xor(cm, 16, 64));
        cm = fmaxf(cm, __shfl_xor(cm, 32, 64));
        float mnew = fmaxf(m_run, cm);
        float sc = __expf(m_run - mnew);
        m_run = mnew;
        float p[4]; float ps = 0.0f;
        #pragma unroll
        for (int r = 0; r < 4; ++r) { p[r] = __expf(lo[r] - mnew); ps += p[r]; }
        ps += __shfl_xor(ps, 16, 64);
        ps += __shfl_xor(ps, 32, 64);
        l_run = l_run * sc + ps;

        // rescale this wave's previously-stored P entries when the max moved
        if (sc != 1.0f) {
            for (int jj = lg * 4; jj < jc * 16; jj += 16) {
                short* pr = &P_lds[m15][jw + jj];
                #pragma unroll
                for (int r = 0; r < 4; ++r) pr[r] = f2b(b2f(pr[r]) * sc);
            }
        }
        *(short4*)&P_lds[m15][jw + jc * 16 + lg * 4] =
            make_short4(f2b(p[0]), f2b(p[1]), f2b(p[2]), f2b(p[3]));

        zAp += 16 * CZ;      // FIX: advance to next 16-j block
        kAp += 16 * 384;
    }

    if (lg == 0) { ml_s[w][m15] = m_run; ll_s[w][m15] = l_run; }
    __syncthreads();
    if (t < 16) {
        float M = ml_s[0][t];
        M = fmaxf(M, ml_s[1][t]); M = fmaxf(M, ml_s[2][t]); M = fmaxf(M, ml_s[3][t]);
        float Lt = 0.0f;
        #pragma unroll
        for (int ww = 0; ww < 4; ++ww) Lt += ll_s[ww][t] * __expf(ml_s[ww][t] - M);
        M_s[t] = M;
        Linv_s[t] = 1.0f / Lt;
    }
    __syncthreads();

    // in-place normalize: thread t -> row h = t>>4, cols [(t&15)*32, +32)
    {
        const int h = t >> 4, j0t = (t & 15) * 32;
        const int wv = j0t >> 7;
        const float sS = __expf(ml_s[wv][h] - M_s[h]) * Linv_s[h];
        #pragma unroll
        for (int k = 0; k < 4; ++k) {
            s16x8 v = *(const s16x8*)&P_lds[h][j0t + k * 8];
            s16x8 o;
            #pragma unroll
            for (int e = 0; e < 8; ++e) o[e] = f2b(b2f(v[e]) * sS);
            *(s16x8*)&P_lds[h][j0t + k * 8] = o;
        }
    }
    __syncthreads();

    // ================= phase 2 =================
    float* F = feat + (size_t)bi * FEAT;

    // ---- opair GEMM: D[h][c] = sum_j P[h][j] * z[j][c]; wave w owns c-tiles
    f32x4 oa0 = (f32x4){0, 0, 0, 0}, oa1 = (f32x4){0, 0, 0, 0};
    const int c0 = w * 32;
    #pragma unroll 4
    for (int kk = 0; kk < 16; ++kk) {
        s16x8 af = *(const s16x8*)&P_lds[m15][kk * 32 + lg * 8];
        const float* zb = z + zbase + (size_t)(kk * 32 + lg * 8) * CZ + c0 + m15;
        s16x8 b0f, b1f;
        #pragma unroll
        for (int e = 0; e < 8; ++e) {
            b0f[e] = f2b(zb[(size_t)e * CZ]);
            b1f[e] = f2b(zb[(size_t)e * CZ + 16]);
        }
        oa0 = __builtin_amdgcn_mfma_f32_16x16x32_bf16(af, b0f, oa0, 0, 0, 0);
        oa1 = __builtin_amdgcn_mfma_f32_16x16x32_bf16(af, b1f, oa1, 0, 0, 0);
    }
    #pragma unroll
    for (int r = 0; r < 4; ++r) {
        int h = lg * 4 + r;
        if (h < 12) {
            F[576 + h * 128 + c0 + m15]      = oa0[r];
            F[576 + h * 128 + c0 + 16 + m15] = oa1[r];
        }
    }

    // ---- o: thread t<192 -> row t (h = t>>4) ----
    if (t < 192) {
        const float* vr = vT + ((size_t)b * 192 + t) * N;
        const short* Pr = &P_lds[t >> 4][0];
        float a = 0.0f;
        for (int q = 0; q < 64; ++q) {
            s16x8 pv = *(const s16x8*)(Pr + q * 8);
            float4 v0 = *(const float4*)(vr + q * 8);
            float4 v1 = *(const float4*)(vr + q * 8 + 4);
            a += b2f(pv[0]) * v0.x + b2f(pv[1]) * v0.y + b2f(pv[2]) * v0.z + b2f(pv[3]) * v0.w
               + b2f(pv[4]) * v1.x + b2f(pv[5]) * v1.y + b2f(pv[6]) * v1.z + b2f(pv[7]) * v1.w;
        }
        F[t] = a;
    }

    // ---- op rows rv < 288: rv = oi*3+x, h = rv/24 ----
    #pragma unroll
    for (int rep = 0; rep < 2; ++rep) {
        int rv = t + rep * 256;
        if (rv < 288) {
            const short* Pr = &P_lds[rv / 24][0];
            const float* vr = vpT + ((size_t)b * 288 + rv) * N;
            float a = 0.0f;
            for (int q = 0; q < 64; ++q) {
                s16x8 pv = *(const s16x8*)(Pr + q * 8);
                float4 v0 = *(const float4*)(vr + q * 8);
                float4 v1 = *(const float4*)(vr + q * 8 + 4);
                a += b2f(pv[0]) * v0.x + b2f(pv[1]) * v0.y + b2f(pv[2]) * v0.z + b2f(pv[3]) * v0.w
                   + b2f(pv[4]) * v1.x + b2f(pv[5]) * v1.y + b2f(pv[6]) * v1.z + b2f(pv[7]) * v1.w;
            }
            op_f[rv] = a;
        }
    }
    __syncthreads();

    if (t < 96) {
        float o0 = op_f[t * 3 + 0] - T_s[0];
        float o1 = op_f[t * 3 + 1] - T_s[1];
        float o2 = op_f[t * 3 + 2] - T_s[2];
        float n2 = 0.0f;
        #pragma unroll
        for (int x = 0; x < 3; ++x) {
            float rx = R_s[0 * 3 + x] * o0 + R_s[1 * 3 + x] * o1 + R_s[2 * 3 + x] * o2; // R^T
            F[HC + 96 * x + t] = rx;
            n2 += rx * rx;
        }
        F[480 + t] = fmaxf(sqrtf(n2), 1e-6f);
    }
}

// ---------------------------------------------------------------------------
// Kernel 3: tiled f32 GEMM  out[1024,384] = feat @ Wout + bout. (unchanged)
// ---------------------------------------------------------------------------
constexpr int BM = 32, BN = 64, KC = 96;
constexpr int FP = 100;

__global__ __launch_bounds__(256) void k_out(
    const float* __restrict__ feat, const float* __restrict__ Wout, const float* __restrict__ bout,
    float* __restrict__ out)
{
    __shared__ float f_s[BM * FP];
    __shared__ float w_s[KC * BN];
    const int t = threadIdx.x;
    const int bm = (blockIdx.x / 6) * BM;
    const int bn = (blockIdx.x % 6) * BN;

    const int cg = t & 15;
    const int rp = t >> 4;
    const int r0 = rp, r1 = rp + 16;

    float4 acc0 = {0, 0, 0, 0}, acc1 = {0, 0, 0, 0};

    for (int k0 = 0; k0 < FEAT; k0 += KC) {
        __syncthreads();
        for (int idx = t; idx < BM * KC / 4; idx += 256) {
            int row = idx / (KC / 4), c4 = idx % (KC / 4);
            *(float4*)&f_s[row * FP + c4 * 4] =
                *(const float4*)&feat[(size_t)(bm + row) * FEAT + k0 + c4 * 4];
        }
        for (int idx = t; idx < KC * BN / 4; idx += 256) {
            int row = idx >> 4, c4 = idx & 15;
            *(float4*)&w_s[row * BN + c4 * 4] =
                *(const float4*)&Wout[(size_t)(k0 + row) * CS + bn + c4 * 4];
        }
        __syncthreads();

        #pragma unroll 4
        for (int kq = 0; kq < KC / 4; ++kq) {
            float4 fa = *(const float4*)&f_s[r0 * FP + kq * 4];
            float4 fb = *(const float4*)&f_s[r1 * FP + kq * 4];
            const float fav[4] = {fa.x, fa.y, fa.z, fa.w};
            const float fbv[4] = {fb.x, fb.y, fb.z, fb.w};
            #pragma unroll
            for (int e = 0; e < 4; ++e) {
                float4 w4 = *(const float4*)&w_s[(kq * 4 + e) * BN + cg * 4];
                acc0.x += fav[e] * w4.x; acc0.y += fav[e] * w4.y;
                acc0.z += fav[e] * w4.z; acc0.w += fav[e] * w4.w;
                acc1.x += fbv[e] * w4.x; acc1.y += fbv[e] * w4.y;
                acc1.z += fbv[e] * w4.z; acc1.w += fbv[e] * w4.w;
            }
        }
    }

    float4 bo = *(const float4*)&bout[bn + cg * 4];
    acc0.x += bo.x; acc0.y += bo.y; acc0.z += bo.z; acc0.w += bo.w;
    acc1.x += bo.x; acc1.y += bo.y; acc1.z += bo.z; acc1.w += bo.w;
    *(float4*)&out[(size_t)(bm + r0) * CS + bn + cg * 4] = acc0;
    *(float4*)&out[(size_t)(bm + r1) * CS + bn + cg * 4] = acc1;
}

// ---------------------------------------------------------------------------
extern "C" void kernel_launch(void* const* d_in, const int* in_sizes, int n_in,
                              void* d_out, int out_size, void* d_ws, size_t ws_size,
                              hipStream_t stream)
{
    const float* s     = (const float*)d_in[0];
    const float* z     = (const float*)d_in[1];
    const float* rot   = (const float*)d_in[2];
    const float* trans = (const float*)d_in[3];
    const float* mask  = (const float*)d_in[4];
    const float* Wq    = (const float*)d_in[5];
    const float* bq    = (const float*)d_in[6];
    const float* Wkv   = (const float*)d_in[7];
    const float* bkv   = (const float*)d_in[8];
    const float* Wb    = (const float*)d_in[9];
    const float* bb    = (const float*)d_in[10];
    const float* Wqp   = (const float*)d_in[11];
    const float* bqp   = (const float*)d_in[12];
    const float* Wkvp  = (const float*)d_in[13];
    const float* bkvp  = (const float*)d_in[14];
    const float* gamma = (const float*)d_in[15];
    const float* Wout  = (const float*)d_in[16];
    const float* bout  = (const float*)d_in[17];

    // workspace layout (bytes), 16B-aligned; total 12,255,232 (proven safe)
    char* wsb = (char*)d_ws;
    float* feat = (float*)wsb;                       // 8,650,752
    float* vT   = (float*)(wsb + 8650752);           //   786,432
    float* vpT  = (float*)(wsb + 9437184);           // 1,179,648
    float* auxw = (float*)(wsb + 10616832);          //    65,536
    short* qcw  = (short*)(wsb + 10682368);          //   393,216
    short* pcw  = (short*)(wsb + 11075584);          //   393,216
    short* kkp  = (short*)(wsb + 11468800);          //   786,432

    dim3 blk(256);
    hipLaunchKernelGGL(k_proj, dim3(B * N / RPB), blk, 0, stream,
                       s, rot, trans, Wq, bq, Wkv, bkv, Wqp, bqp, Wkvp, bkvp,
                       gamma, bb, qcw, kkp, vT, vpT, pcw, auxw);
    hipLaunchKernelGGL(k_attn2, dim3(B * N), blk, 0, stream,
                       z, rot, trans, mask, Wb, qcw, kkp, pcw, auxw, vT, vpT, feat);
    hipLaunchKernelGGL(k_out, dim3(192), blk, 0, stream,
                       feat, Wout, bout, (float*)d_out);
}

// Round 8
// 446.190 us; speedup vs baseline: 2.7527x; 1.2595x over previous
//
#include <hip/hip_runtime.h>
#include <hip/hip_bf16.h>

// Shapes (fixed for this problem)
constexpr int B = 2, N = 512, H = 12, C = 16, PQ = 4, PV = 8, CZ = 128, CS = 384;
constexpr int HC   = H * C;            // 192
constexpr int FEAT = (CZ + C + PV * 4) * H; // 2112
constexpr float QK_SCALE  = 0.14433756729740643f;  // (3*C)^-0.5
constexpr float INV_SQRT3 = 0.5773502691896258f;
constexpr float WC_IS3    = 0.13608276348795434f;  // sqrt(2/(9*PQ))*3^-0.5

using f32x4 = __attribute__((ext_vector_type(4))) float;
using s16x8 = __attribute__((ext_vector_type(8))) short;

__device__ __forceinline__ short f2b(float f) {
    union { __hip_bfloat16 b; short s; } u;
    u.b = __float2bfloat16(f);
    return u.s;
}
__device__ __forceinline__ float b2f(short s) {
    union { short s; __hip_bfloat16 b; } u;
    u.s = s;
    return __bfloat162float(u.b);
}

// ---------------------------------------------------------------------------
// Kernel 0: WoutT bf16 [384][2112] = transpose+convert of Wout f32 [2112][384]
// ---------------------------------------------------------------------------
__global__ __launch_bounds__(256) void k_wcvt(
    const float* __restrict__ Wout, short* __restrict__ WT)
{
    __shared__ short tile[32 * 33];
    const int t = threadIdx.x;
    const int k0 = (blockIdx.x % 66) * 32;
    const int c0 = (blockIdx.x / 66) * 32;
    {
        int r = t >> 3, c4 = (t & 7) * 4;
        float4 v = *(const float4*)&Wout[(size_t)(k0 + r) * CS + c0 + c4];
        tile[(c4 + 0) * 33 + r] = f2b(v.x);
        tile[(c4 + 1) * 33 + r] = f2b(v.y);
        tile[(c4 + 2) * 33 + r] = f2b(v.z);
        tile[(c4 + 3) * 33 + r] = f2b(v.w);
    }
    __syncthreads();
    {
        int rr = t >> 3, k4 = (t & 7) * 4;
        short4 o = make_short4(tile[rr * 33 + k4], tile[rr * 33 + k4 + 1],
                               tile[rr * 33 + k4 + 2], tile[rr * 33 + k4 + 3]);
        *(short4*)&WT[(size_t)(c0 + rr) * FEAT + k0 + k4] = o;
    }
}

// ---------------------------------------------------------------------------
// Kernel 1: projections + packing. RPB=4 rows/block, 256 blocks.
// Thread owns 4 output cols (float4 W loads); 1 B LDS / FLOP.
// ---------------------------------------------------------------------------
constexpr int RPB = 4;

__global__ __launch_bounds__(256) void k_proj(
    const float* __restrict__ s, const float* __restrict__ rot, const float* __restrict__ trans,
    const float* __restrict__ Wq, const float* __restrict__ bq,
    const float* __restrict__ Wkv, const float* __restrict__ bkv,
    const float* __restrict__ Wqp, const float* __restrict__ bqp,
    const float* __restrict__ Wkvp, const float* __restrict__ bkvp,
    const float* __restrict__ gamma, const float* __restrict__ bb,
    short* __restrict__ qcw, short* __restrict__ kkp,
    float* __restrict__ vT, float* __restrict__ vpT,
    short* __restrict__ pcw, float* __restrict__ auxw)
{
    __shared__ float s_s[RPB][CS];
    __shared__ float rawqp_s[RPB][144];
    __shared__ float rawkvp_s[RPB][432];
    __shared__ float qrot_s[RPB][48][3];
    __shared__ float sq_s[RPB][48];
    __shared__ float R_s[RPB][9], T_s[RPB][3];
    const int t = threadIdx.x;
    const int bi0 = blockIdx.x * RPB;

    for (int idx = t; idx < RPB * CS / 4; idx += 256) {
        int r = idx / (CS / 4), k4 = idx % (CS / 4);
        ((float4*)s_s[r])[k4] = ((const float4*)(s + (size_t)(bi0 + r) * CS))[k4];
    }
    if (t < RPB * 9) R_s[t / 9][t % 9] = rot[bi0 * 9 + t];
    if (t < RPB * 3) T_s[t / 3][t % 3] = trans[bi0 * 3 + t];
    __syncthreads();

    // phase B: 288 col-quads; thread owns quad(s)
    for (int qd = t; qd < 288; qd += 256) {
        const int c = qd * 4;
        const float* Wp; int ldw; const float* bp;
        int seg;
        if (c < 192)      { Wp = Wq   + c;        ldw = 192; bp = bq + c;        seg = 0; }
        else if (c < 576) { Wp = Wkv  + (c - 192); ldw = 384; bp = bkv + (c - 192); seg = 1; }
        else if (c < 720) { Wp = Wqp  + (c - 576); ldw = 144; bp = bqp + (c - 576); seg = 2; }
        else              { Wp = Wkvp + (c - 720); ldw = 432; bp = bkvp + (c - 720); seg = 3; }
        float4 bv = *(const float4*)bp;
        float acc[RPB][4];
        #pragma unroll
        for (int r = 0; r < RPB; ++r) {
            acc[r][0] = bv.x; acc[r][1] = bv.y; acc[r][2] = bv.z; acc[r][3] = bv.w;
        }
        for (int k4 = 0; k4 < CS / 4; ++k4) {
            float4 sv[RPB];
            #pragma unroll
            for (int r = 0; r < RPB; ++r) sv[r] = *(const float4*)&s_s[r][k4 * 4];
            #pragma unroll
            for (int e = 0; e < 4; ++e) {
                float4 wv = *(const float4*)(Wp + (size_t)(k4 * 4 + e) * ldw);
                #pragma unroll
                for (int r = 0; r < RPB; ++r) {
                    float se = ((const float*)&sv[r])[e];
                    acc[r][0] += se * wv.x; acc[r][1] += se * wv.y;
                    acc[r][2] += se * wv.z; acc[r][3] += se * wv.w;
                }
            }
        }
        if (seg == 0) {
            #pragma unroll
            for (int r = 0; r < RPB; ++r) {
                short4 o = make_short4(f2b(QK_SCALE * acc[r][0]), f2b(QK_SCALE * acc[r][1]),
                                       f2b(QK_SCALE * acc[r][2]), f2b(QK_SCALE * acc[r][3]));
                *(short4*)&qcw[(size_t)(bi0 + r) * 192 + c] = o;
            }
        } else if (seg == 1) {
            int cc = c - 192, h = cc >> 5, w5 = cc & 31;
            if (w5 < 16) {
                #pragma unroll
                for (int r = 0; r < RPB; ++r) {
                    short4 o = make_short4(f2b(acc[r][0]), f2b(acc[r][1]),
                                           f2b(acc[r][2]), f2b(acc[r][3]));
                    *(short4*)&kkp[(size_t)(bi0 + r) * 384 + h * 16 + w5] = o;
                }
            } else {
                #pragma unroll
                for (int r = 0; r < RPB; ++r) {
                    int row = bi0 + r, bq_ = row >> 9, iq = row & (N - 1);
                    #pragma unroll
                    for (int x = 0; x < 4; ++x)
                        vT[((size_t)bq_ * 192 + h * 16 + (w5 - 16) + x) * N + iq] = acc[r][x];
                }
            }
        } else if (seg == 2) {
            #pragma unroll
            for (int r = 0; r < RPB; ++r)
                *(float4*)&rawqp_s[r][c - 576] = (float4){acc[r][0], acc[r][1], acc[r][2], acc[r][3]};
        } else {
            #pragma unroll
            for (int r = 0; r < RPB; ++r)
                *(float4*)&rawkvp_s[r][c - 720] = (float4){acc[r][0], acc[r][1], acc[r][2], acc[r][3]};
        }
    }
    __syncthreads();

    for (int idx = t; idx < RPB * 48; idx += 256) {
        int r = idx / 48, p = idx % 48;
        float y0 = rawqp_s[r][p], y1 = rawqp_s[r][48 + p], y2 = rawqp_s[r][96 + p];
        #pragma unroll
        for (int x = 0; x < 3; ++x)
            qrot_s[r][p][x] = T_s[r][x] + R_s[r][x * 3] * y0 + R_s[r][x * 3 + 1] * y1 + R_s[r][x * 3 + 2] * y2;
    }
    for (int idx = t; idx < RPB * 144; idx += 256) {
        int r = idx / 144, p = idx % 144, h = p / 12, pp = p % 12;
        float y0 = rawkvp_s[r][p], y1 = rawkvp_s[r][144 + p], y2 = rawkvp_s[r][288 + p];
        float vals[3]; float ss = 0.0f;
        #pragma unroll
        for (int x = 0; x < 3; ++x) {
            float v = T_s[r][x] + R_s[r][x * 3] * y0 + R_s[r][x * 3 + 1] * y1 + R_s[r][x * 3 + 2] * y2;
            vals[x] = v; ss += v * v;
        }
        int row = bi0 + r, bq_ = row >> 9, iq = row & (N - 1);
        if (pp < PQ) {
            #pragma unroll
            for (int x = 0; x < 3; ++x)
                kkp[(size_t)row * 384 + 192 + h * 16 + pp * 3 + x] = f2b(vals[x]);
            sq_s[r][h * 4 + pp] = ss;
        } else {
            #pragma unroll
            for (int x = 0; x < 3; ++x)
                vpT[((size_t)bq_ * 288 + h * 24 + (pp - PQ) * 3 + x) * N + iq] = vals[x];
        }
    }
    __syncthreads();

    if (t < RPB * 12) {
        int r = t / 12, h = t % 12, row = bi0 + r;
        float g = gamma[h];
        float sp = fmaxf(g, 0.0f) + log1pf(expf(-fabsf(g)));
        float pac = -0.5f * sp * WC_IS3;
        float kpsq = sq_s[r][h * 4] + sq_s[r][h * 4 + 1] + sq_s[r][h * 4 + 2] + sq_s[r][h * 4 + 3];
        kkp[(size_t)row * 384 + 192 + h * 16 + 12] = f2b(kpsq);
        kkp[(size_t)row * 384 + 192 + h * 16 + 13] = 0;
        kkp[(size_t)row * 384 + 192 + h * 16 + 14] = 0;
        kkp[(size_t)row * 384 + 192 + h * 16 + 15] = 0;
        float qpsq = 0.0f;
        #pragma unroll
        for (int pq = 0; pq < 4; ++pq)
            #pragma unroll
            for (int x = 0; x < 3; ++x) {
                float qv = qrot_s[r][h * 4 + pq][x];
                qpsq += qv * qv;
                pcw[(size_t)row * 192 + h * 16 + pq * 3 + x] = f2b(-2.0f * pac * qv);
            }
        pcw[(size_t)row * 192 + h * 16 + 12] = f2b(pac);
        pcw[(size_t)row * 192 + h * 16 + 13] = 0;
        pcw[(size_t)row * 192 + h * 16 + 14] = 0;
        pcw[(size_t)row * 192 + h * 16 + 15] = 0;
        auxw[(size_t)row * 16 + h] = INV_SQRT3 * bb[h] + pac * qpsq;
    }
    if (t >= RPB * 12 && t < RPB * 16) {
        int r = (t - RPB * 12) >> 2, hh = 12 + ((t - RPB * 12) & 3);
        auxw[(size_t)(bi0 + r) * 16 + hh] = 0.0f;
    }
}

// ---------------------------------------------------------------------------
// Kernel 2: fused attention. 512 threads = 8 waves; wave owns 64 j (4 chunks).
// P_lds stride 520 (bank-conflict-free). feat written bf16.
// ---------------------------------------------------------------------------
constexpr int PLS = 520;   // P_lds row stride in shorts

__global__ __launch_bounds__(512) void k_attn2(
    const float* __restrict__ z, const float* __restrict__ rot, const float* __restrict__ trans,
    const float* __restrict__ seq_mask,
    const float* __restrict__ Wb,
    const short* __restrict__ qcw, const short* __restrict__ kkp,
    const short* __restrict__ pcw, const float* __restrict__ auxw,
    const float* __restrict__ vT, const float* __restrict__ vpT,
    short* __restrict__ featb)
{
    __shared__ short P_lds[16 * PLS];       // 16.6 KB
    __shared__ float ml_s[8][16], ll_s[8][16], M_s[16], Linv_s[16];
    __shared__ float op_f[288];
    __shared__ float R_s[9], T_s[3];

    const int t = threadIdx.x;
    const int w   = t >> 6;          // 0..7
    const int l   = t & 63;
    const int lg  = l >> 4;
    const int m15 = l & 15;
    const int bi  = blockIdx.x;
    const int b   = bi >> 9;
    const int i   = bi & (N - 1);

    if (t < 9) R_s[t] = rot[bi * 9 + t];
    if (t < 3) T_s[t] = trans[bi * 3 + t];

    const bool hv = (m15 < 12);
    const int hcl = hv ? m15 : 0;
    const int half = m15 >> 1;
    const float constH = auxw[(size_t)bi * 16 + m15];
    const float mask_i = seq_mask[bi];

    const s16x8 z8 = {0, 0, 0, 0, 0, 0, 0, 0};
    s16x8 WbB[4];
    #pragma unroll
    for (int kk = 0; kk < 4; ++kk) {
        s16x8 f;
        #pragma unroll
        for (int e = 0; e < 8; ++e) {
            int c = kk * 32 + lg * 8 + e;
            f[e] = f2b(hv ? INV_SQRT3 * Wb[c * H + hcl] : 0.0f);
        }
        WbB[kk] = f;
    }
    s16x8 qsel, psel;
    {
        const bool selh = ((lg >> 1) == (m15 & 1));
        const short* qrow = qcw + (size_t)bi * 192 + hcl * 16;
        s16x8 qlo = *(const s16x8*)qrow;
        s16x8 qhi = *(const s16x8*)(qrow + 8);
        qsel = (hv && selh) ? ((lg & 1) ? qhi : qlo) : z8;
        const short* prow = pcw + (size_t)bi * 192 + hcl * 16;
        s16x8 plo = *(const s16x8*)prow;
        s16x8 phi = *(const s16x8*)(prow + 8);
        psel = (hv && selh) ? ((lg & 1) ? phi : plo) : z8;
    }

    float m_run = -INFINITY, l_run = 0.0f;

    const size_t zbase = ((size_t)b * N + i) * (size_t)(N * CZ);
    const int jw = w * 64;
    const float* zAp = z + zbase + (size_t)(jw + m15) * CZ + lg * 8;
    const short* kAp = kkp + (size_t)(b * N + jw + m15) * 384 + lg * 8;
    const float* mkp = seq_mask + b * N + jw + lg * 4;

    for (int jc = 0; jc < 4; ++jc) {
        // ---- A-fragments ----
        s16x8 zf[4];
        #pragma unroll
        for (int kk = 0; kk < 4; ++kk) {
            float4 u0 = *(const float4*)(zAp + kk * 32);
            float4 u1 = *(const float4*)(zAp + kk * 32 + 4);
            s16x8 f;
            f[0] = f2b(u0.x); f[1] = f2b(u0.y); f[2] = f2b(u0.z); f[3] = f2b(u0.w);
            f[4] = f2b(u1.x); f[5] = f2b(u1.y); f[6] = f2b(u1.z); f[7] = f2b(u1.w);
            zf[kk] = f;
        }
        s16x8 kkpf[12];
        #pragma unroll
        for (int kk = 0; kk < 12; ++kk) kkpf[kk] = *(const s16x8*)(kAp + kk * 32);

        // ---- chained logit MFMAs: D[j][h] ----
        f32x4 acc = (f32x4){0.0f, 0.0f, 0.0f, 0.0f};
        #pragma unroll
        for (int kk = 0; kk < 4; ++kk)
            acc = __builtin_amdgcn_mfma_f32_16x16x32_bf16(zf[kk], WbB[kk], acc, 0, 0, 0);
        #pragma unroll
        for (int kk = 0; kk < 12; ++kk) {
            s16x8 bsel;
            if (kk < 6) bsel = (kk == half) ? qsel : z8;
            else        bsel = ((kk - 6) == half) ? psel : z8;
            acc = __builtin_amdgcn_mfma_f32_16x16x32_bf16(kkpf[kk], bsel, acc, 0, 0, 0);
        }

        // ---- softmax (lane: h=m15, j = jw + jc*16 + lg*4 + r) ----
        float4 m4 = *(const float4*)(mkp + jc * 16);
        float lo[4]; float cm = -INFINITY;
        #pragma unroll
        for (int r = 0; r < 4; ++r) {
            lo[r] = acc[r] + constH + 100000.0f * (mask_i * ((const float*)&m4)[r] - 1.0f);
            cm = fmaxf(cm, lo[r]);
        }
        cm = fmaxf(cm, __shfl_xor(cm, 16, 64));
        cm = fmaxf(cm, __shfl_xor(cm, 32, 64));
        float mnew = fmaxf(m_run, cm);
        float sc = __expf(m_run - mnew);
        m_run = mnew;
        float p[4]; float ps = 0.0f;
        #pragma unroll
        for (int r = 0; r < 4; ++r) { p[r] = __expf(lo[r] - mnew); ps += p[r]; }
        ps += __shfl_xor(ps, 16, 64);
        ps += __shfl_xor(ps, 32, 64);
        l_run = l_run * sc + ps;

        // rescale this wave's previously-stored P entries when the max moved
        if (sc != 1.0f) {
            for (int jj = lg * 4; jj < jc * 16; jj += 16) {
                short* pr = &P_lds[m15 * PLS + jw + jj];
                #pragma unroll
                for (int r = 0; r < 4; ++r) pr[r] = f2b(b2f(pr[r]) * sc);
            }
        }
        *(short4*)&P_lds[m15 * PLS + jw + jc * 16 + lg * 4] =
            make_short4(f2b(p[0]), f2b(p[1]), f2b(p[2]), f2b(p[3]));

        zAp += 16 * CZ;
        kAp += 16 * 384;
    }

    if (lg == 0) { ml_s[w][m15] = m_run; ll_s[w][m15] = l_run; }
    __syncthreads();
    if (t < 16) {
        float M = ml_s[0][t];
        #pragma unroll
        for (int ww = 1; ww < 8; ++ww) M = fmaxf(M, ml_s[ww][t]);
        float Lt = 0.0f;
        #pragma unroll
        for (int ww = 0; ww < 8; ++ww) Lt += ll_s[ww][t] * __expf(ml_s[ww][t] - M);
        M_s[t] = M;
        Linv_s[t] = 1.0f / Lt;
    }
    __syncthreads();

    // in-place normalize: thread t -> row h = t>>5, cols [(t&31)*16, +16)
    {
        const int h = t >> 5, j0t = (t & 31) * 16;
        const int wv = j0t >> 6;
        const float sS = __expf(ml_s[wv][h] - M_s[h]) * Linv_s[h];
        #pragma unroll
        for (int k = 0; k < 2; ++k) {
            s16x8 v = *(const s16x8*)&P_lds[h * PLS + j0t + k * 8];
            s16x8 o;
            #pragma unroll
            for (int e = 0; e < 8; ++e) o[e] = f2b(b2f(v[e]) * sS);
            *(s16x8*)&P_lds[h * PLS + j0t + k * 8] = o;
        }
    }
    __syncthreads();

    // ================= phase 2 =================
    short* F = featb + (size_t)bi * FEAT;

    // ---- opair GEMM: D[h][c]; wave w owns 16-col tile c0 = w*16 ----
    f32x4 oa0 = (f32x4){0, 0, 0, 0};
    const int c0 = w * 16;
    #pragma unroll 4
    for (int kk = 0; kk < 16; ++kk) {
        s16x8 af = *(const s16x8*)&P_lds[m15 * PLS + kk * 32 + lg * 8];
        const float* zb = z + zbase + (size_t)(kk * 32 + lg * 8) * CZ + c0 + m15;
        s16x8 bfr;
        #pragma unroll
        for (int e = 0; e < 8; ++e) bfr[e] = f2b(zb[(size_t)e * CZ]);
        oa0 = __builtin_amdgcn_mfma_f32_16x16x32_bf16(af, bfr, oa0, 0, 0, 0);
    }
    #pragma unroll
    for (int r = 0; r < 4; ++r) {
        int h = lg * 4 + r;
        if (h < 12) F[576 + h * 128 + c0 + m15] = f2b(oa0[r]);
    }

    // ---- o: thread t<192 -> row t (h = t>>4) ----
    if (t < 192) {
        const float* vr = vT + ((size_t)b * 192 + t) * N;
        const short* Pr = &P_lds[(t >> 4) * PLS];
        float a = 0.0f;
        for (int q = 0; q < 64; ++q) {
            s16x8 pv = *(const s16x8*)(Pr + q * 8);
            float4 v0 = *(const float4*)(vr + q * 8);
            float4 v1 = *(const float4*)(vr + q * 8 + 4);
            a += b2f(pv[0]) * v0.x + b2f(pv[1]) * v0.y + b2f(pv[2]) * v0.z + b2f(pv[3]) * v0.w
               + b2f(pv[4]) * v1.x + b2f(pv[5]) * v1.y + b2f(pv[6]) * v1.z + b2f(pv[7]) * v1.w;
        }
        F[t] = f2b(a);
    }

    // ---- op rows: t in [192,480) -> rv = t-192; h = rv/24 ----
    if (t >= 192 && t < 480) {
        int rv = t - 192;
        const short* Pr = &P_lds[(rv / 24) * PLS];
        const float* vr = vpT + ((size_t)b * 288 + rv) * N;
        float a = 0.0f;
        for (int q = 0; q < 64; ++q) {
            s16x8 pv = *(const s16x8*)(Pr + q * 8);
            float4 v0 = *(const float4*)(vr + q * 8);
            float4 v1 = *(const float4*)(vr + q * 8 + 4);
            a += b2f(pv[0]) * v0.x + b2f(pv[1]) * v0.y + b2f(pv[2]) * v0.z + b2f(pv[3]) * v0.w
               + b2f(pv[4]) * v1.x + b2f(pv[5]) * v1.y + b2f(pv[6]) * v1.z + b2f(pv[7]) * v1.w;
        }
        op_f[rv] = a;
    }
    __syncthreads();

    if (t < 96) {
        float o0 = op_f[t * 3 + 0] - T_s[0];
        float o1 = op_f[t * 3 + 1] - T_s[1];
        float o2 = op_f[t * 3 + 2] - T_s[2];
        float n2 = 0.0f;
        #pragma unroll
        for (int x = 0; x < 3; ++x) {
            float rx = R_s[0 * 3 + x] * o0 + R_s[1 * 3 + x] * o1 + R_s[2 * 3 + x] * o2; // R^T
            F[HC + 96 * x + t] = f2b(rx);
            n2 += rx * rx;
        }
        F[480 + t] = f2b(fmaxf(sqrtf(n2), 1e-6f));
    }
}

// ---------------------------------------------------------------------------
// Kernel 3: bf16 MFMA GEMM out[1024,384] = featb @ WoutT^T + bout (f32 out).
// BM=BN=64, K-step 32, 4 waves (2x2), wave tile 32x32.
// ---------------------------------------------------------------------------
__global__ __launch_bounds__(256) void k_out(
    const short* __restrict__ featb, const short* __restrict__ WT,
    const float* __restrict__ bout, float* __restrict__ out)
{
    __shared__ short A_s[64 * 40];
    __shared__ short B_s[64 * 40];
    const int t = threadIdx.x;
    const int w   = t >> 6;
    const int l   = t & 63;
    const int lg  = l >> 4;
    const int m15 = l & 15;
    const int wm = w >> 1, wn = w & 1;
    const int bm = (blockIdx.x / 6) * 64;
    const int bn = (blockIdx.x % 6) * 64;

    f32x4 acc[2][2];
    #pragma unroll
    for (int sm = 0; sm < 2; ++sm)
        #pragma unroll
        for (int sn = 0; sn < 2; ++sn) acc[sm][sn] = (f32x4){0, 0, 0, 0};

    const int sr = t >> 2;            // 0..63 staging row
    const int sk = (t & 3) * 8;       // staging k-offset

    for (int k0 = 0; k0 < FEAT; k0 += 32) {
        __syncthreads();
        *(s16x8*)&A_s[sr * 40 + sk] = *(const s16x8*)&featb[(size_t)(bm + sr) * FEAT + k0 + sk];
        *(s16x8*)&B_s[sr * 40 + sk] = *(const s16x8*)&WT[(size_t)(bn + sr) * FEAT + k0 + sk];
        __syncthreads();

        s16x8 af[2], bf[2];
        #pragma unroll
        for (int sm = 0; sm < 2; ++sm)
            af[sm] = *(const s16x8*)&A_s[(wm * 32 + sm * 16 + m15) * 40 + lg * 8];
        #pragma unroll
        for (int sn = 0; sn < 2; ++sn)
            bf[sn] = *(const s16x8*)&B_s[(wn * 32 + sn * 16 + m15) * 40 + lg * 8];
        #pragma unroll
        for (int sm = 0; sm < 2; ++sm)
            #pragma unroll
            for (int sn = 0; sn < 2; ++sn)
                acc[sm][sn] = __builtin_amdgcn_mfma_f32_16x16x32_bf16(af[sm], bf[sn], acc[sm][sn], 0, 0, 0);
    }

    #pragma unroll
    for (int sn = 0; sn < 2; ++sn) {
        int col = bn + wn * 32 + sn * 16 + m15;
        float bo = bout[col];
        #pragma unroll
        for (int sm = 0; sm < 2; ++sm)
            #pragma unroll
            for (int r = 0; r < 4; ++r) {
                int row = bm + wm * 32 + sm * 16 + lg * 4 + r;
                out[(size_t)row * CS + col] = acc[sm][sn][r] + bo;
            }
    }
}

// ---------------------------------------------------------------------------
extern "C" void kernel_launch(void* const* d_in, const int* in_sizes, int n_in,
                              void* d_out, int out_size, void* d_ws, size_t ws_size,
                              hipStream_t stream)
{
    const float* s     = (const float*)d_in[0];
    const float* z     = (const float*)d_in[1];
    const float* rot   = (const float*)d_in[2];
    const float* trans = (const float*)d_in[3];
    const float* mask  = (const float*)d_in[4];
    const float* Wq    = (const float*)d_in[5];
    const float* bq    = (const float*)d_in[6];
    const float* Wkv   = (const float*)d_in[7];
    const float* bkv   = (const float*)d_in[8];
    const float* Wb    = (const float*)d_in[9];
    const float* bb    = (const float*)d_in[10];
    const float* Wqp   = (const float*)d_in[11];
    const float* bqp   = (const float*)d_in[12];
    const float* Wkvp  = (const float*)d_in[13];
    const float* bkvp  = (const float*)d_in[14];
    const float* gamma = (const float*)d_in[15];
    const float* Wout  = (const float*)d_in[16];
    const float* bout  = (const float*)d_in[17];

    // workspace layout (bytes), 16B-aligned; total 9,551,872 (< proven 12.25 MB)
    char* wsb = (char*)d_ws;
    short* featb = (short*)wsb;                      // 4,325,376
    float* vT    = (float*)(wsb + 4325376);          //   786,432
    float* vpT   = (float*)(wsb + 5111808);          // 1,179,648
    float* auxw  = (float*)(wsb + 6291456);          //    65,536
    short* qcw   = (short*)(wsb + 6356992);          //   393,216
    short* pcw   = (short*)(wsb + 6750208);          //   393,216
    short* kkp   = (short*)(wsb + 7143424);          //   786,432
    short* WT    = (short*)(wsb + 7929856);          // 1,622,016

    hipLaunchKernelGGL(k_wcvt, dim3(66 * 12), dim3(256), 0, stream, Wout, WT);
    hipLaunchKernelGGL(k_proj, dim3(B * N / RPB), dim3(256), 0, stream,
                       s, rot, trans, Wq, bq, Wkv, bkv, Wqp, bqp, Wkvp, bkvp,
                       gamma, bb, qcw, kkp, vT, vpT, pcw, auxw);
    hipLaunchKernelGGL(k_attn2, dim3(B * N), dim3(512), 0, stream,
                       z, rot, trans, mask, Wb, qcw, kkp, pcw, auxw, vT, vpT, featb);
    hipLaunchKernelGGL(k_out, dim3(96), dim3(256), 0, stream,
                       featb, WT, bout, (float*)d_out);
}